// Round 8
// baseline (149.163 us; speedup 1.0000x reference)
//
#include <hip/hip_runtime.h>

#define DI static __device__ __forceinline__

typedef __attribute__((ext_vector_type(8))) short short8;    // 8 bf16 in 4 VGPRs
typedef __attribute__((ext_vector_type(4))) float f32x4;
typedef __attribute__((ext_vector_type(16))) float f32x16;

// fp32 -> bf16 round-to-nearest-even
DI unsigned short f2bf(float f) {
    union { float f; unsigned int u; } v; v.f = f;
    unsigned int r = v.u + 0x7FFFu + ((v.u >> 16) & 1u);
    return (unsigned short)(r >> 16);
}

// async global->LDS, 16B per lane. LDS dest must be wave-uniform base + lane*16.
DI void gload_lds16(const void* g, void* l) {
    __builtin_amdgcn_global_load_lds(
        (const __attribute__((address_space(1))) void*)g,
        (__attribute__((address_space(3))) void*)l, 16, 0, 0);
}

// swizzled LDS fragment read for 128B-row tiles (attention)
DI short8 ldsfrag(const void* base, int row, int bytecol) {
    return *(const short8*)((const char*)base + row * 128 + (bytecol ^ ((row & 7) << 4)));
}

// ---------------------------------------------------------------------------
// Kernel 1: fp32 -> bf16 conversion, flat 1D grid (x 8M elems, 4 x 1M weights)
// ---------------------------------------------------------------------------
__global__ __launch_bounds__(256) void k_cvt(
    const float* __restrict__ x, const float* __restrict__ wq,
    const float* __restrict__ wk, const float* __restrict__ wv,
    const float* __restrict__ wo,
    unsigned short* __restrict__ xb, unsigned short* __restrict__ wqb,
    unsigned short* __restrict__ wkb, unsigned short* __restrict__ wvb,
    unsigned short* __restrict__ wob)
{
    int idx = (blockIdx.x * 256 + threadIdx.x) * 4;   // < 12582912
    const float* src; unsigned short* dst; int off;
    if (idx < 8388608) {
        src = x; dst = xb; off = idx;
    } else {
        int rel = idx - 8388608;
        int sel = rel >> 20;
        off = rel & 1048575;
        switch (sel) {
            case 0:  src = wq; dst = wqb; break;
            case 1:  src = wk; dst = wkb; break;
            case 2:  src = wv; dst = wvb; break;
            default: src = wo; dst = wob; break;
        }
    }
    float4 v = *(const float4*)(src + off);
    unsigned long long o = (unsigned long long)f2bf(v.x)
        | ((unsigned long long)f2bf(v.y) << 16)
        | ((unsigned long long)f2bf(v.z) << 32)
        | ((unsigned long long)f2bf(v.w) << 48);
    *(unsigned long long*)(dst + off) = o;
}

// ---------------------------------------------------------------------------
// 128x256 GEMM core, BK=32, K=1024, 32x32x16 MFMA. C[i][j]=sum_k A[i][k]B[j][k].
// 4 waves (1M x 4N), per-wave C = 128x64 = 4x2 32x32 frags (f32x16 each).
// 3 LDS buffers x (A 8KB + B 16KB) = 72KB -> 2 blocks/CU. Counted-vmcnt
// schedule UNCHANGED from R5-R7 (proven race-free):
//   body ks: vmcnt(6) -> s_barrier -> frag reads (slice0) -> issue tile ks+2
//            -> frag reads (slice1) -> 16 MFMA (setprio-wrapped).
// LDS rows 64B; staging slot-swizzle slot^=(row>>1)&3 IDENTICAL to R5-R7.
// Fragment read: row=lane&31 (+32*mi / +32*nj+64*wc), k-slot (ks2*2+hi2)
// XOR (lane>>1)&3 -> 2 lanes/bank = conflict-free.
// C/D layout (m74/m101): col=lane&31, row=(reg&3)+8*(reg>>2)+4*(lane>>5).
// ---------------------------------------------------------------------------
DI void gemm_core(const unsigned short* __restrict__ Ag,
                  const unsigned short* __restrict__ Bg,
                  int m0, int n0, char* smem, f32x16 acc[4][2])
{
    const int t = threadIdx.x, lane = t & 63;
    const int wc = t >> 6;                 // wave = N-quadrant (all waves share M)
    const int l31 = lane & 31, hi2 = lane >> 5;

#pragma unroll
    for (int m = 0; m < 4; ++m)
#pragma unroll
        for (int n = 0; n < 2; ++n)
#pragma unroll
            for (int q = 0; q < 16; ++q) acc[m][n][q] = 0.f;

    // staging (identical to R5-R7): A = 512 chunks of 16B (2/thread),
    // B = 1024 chunks (4/thread); chunk c: row=c>>2, slot=c&3,
    // src slot = slot ^ ((row>>1)&3)
    const int ca0 = t,       ra0 = ca0 >> 2, sa0 = ((ca0 & 3) ^ ((ra0 >> 1) & 3)) * 8;
    const int ca1 = t + 256, ra1 = ca1 >> 2, sa1 = ((ca1 & 3) ^ ((ra1 >> 1) & 3)) * 8;
    const int cb0 = t,       rb0 = cb0 >> 2, sb0 = ((cb0 & 3) ^ ((rb0 >> 1) & 3)) * 8;
    const int cb1 = t + 256, rb1 = cb1 >> 2, sb1 = ((cb1 & 3) ^ ((rb1 >> 1) & 3)) * 8;
    const int cb2 = t + 512, rb2 = cb2 >> 2, sb2 = ((cb2 & 3) ^ ((rb2 >> 1) & 3)) * 8;
    const int cb3 = t + 768, rb3 = cb3 >> 2, sb3 = ((cb3 & 3) ^ ((rb3 >> 1) & 3)) * 8;
    const unsigned short* pa0 = Ag + (long)(m0 + ra0) * 1024 + sa0;
    const unsigned short* pa1 = Ag + (long)(m0 + ra1) * 1024 + sa1;
    const unsigned short* pb0 = Bg + (long)(n0 + rb0) * 1024 + sb0;
    const unsigned short* pb1 = Bg + (long)(n0 + rb1) * 1024 + sb1;
    const unsigned short* pb2 = Bg + (long)(n0 + rb2) * 1024 + sb2;
    const unsigned short* pb3 = Bg + (long)(n0 + rb3) * 1024 + sb3;

#define STAGE(TILE, BUF) do {                                          \
        char* _sb = smem + (BUF) * 24576;                              \
        gload_lds16(pa0 + (TILE) * 32, _sb + ca0 * 16);                \
        gload_lds16(pa1 + (TILE) * 32, _sb + ca1 * 16);                \
        gload_lds16(pb0 + (TILE) * 32, _sb + 8192 + cb0 * 16);         \
        gload_lds16(pb1 + (TILE) * 32, _sb + 8192 + cb1 * 16);        \
        gload_lds16(pb2 + (TILE) * 32, _sb + 8192 + cb2 * 16);        \
        gload_lds16(pb3 + (TILE) * 32, _sb + 8192 + cb3 * 16);        \
    } while (0)

    // prologue: tiles 0 and 1 in flight
    STAGE(0, 0);
    STAGE(1, 1);

    // fragment geometry: row byte-base + XOR'd k-slot offset per k-slice
    const int swz = ((lane >> 1) & 3) << 4;
    const int abase = l31 * 64;                          // + mi*2048
    const int bbase = 8192 + (wc * 64 + l31) * 64;       // + nj*2048
    const int o0 = (hi2 * 16) ^ swz;                     // k-slice 0
    const int o1 = (32 + hi2 * 16) ^ swz;                // k-slice 1

#define KSTEP(KS, CUR, PRE, ISSUE, VM) do {                                   \
        asm volatile("s_waitcnt vmcnt(" VM ")" ::: "memory");                 \
        __builtin_amdgcn_s_barrier();                                         \
        __builtin_amdgcn_sched_barrier(0);                                    \
        const char* _tb = smem + (CUR) * 24576;                               \
        short8 fa0[4], fb0[2], fa1[4], fb1[2];                                \
        _Pragma("unroll")                                                     \
        for (int mi = 0; mi < 4; ++mi)                                        \
            fa0[mi] = *(const short8*)(_tb + abase + mi * 2048 + o0);         \
        _Pragma("unroll")                                                     \
        for (int nj = 0; nj < 2; ++nj)                                        \
            fb0[nj] = *(const short8*)(_tb + bbase + nj * 2048 + o0);         \
        if (ISSUE) STAGE((KS) + 2, PRE);                                      \
        _Pragma("unroll")                                                     \
        for (int mi = 0; mi < 4; ++mi)                                        \
            fa1[mi] = *(const short8*)(_tb + abase + mi * 2048 + o1);         \
        _Pragma("unroll")                                                     \
        for (int nj = 0; nj < 2; ++nj)                                        \
            fb1[nj] = *(const short8*)(_tb + bbase + nj * 2048 + o1);         \
        __builtin_amdgcn_s_setprio(1);                                        \
        _Pragma("unroll")                                                     \
        for (int mi = 0; mi < 4; ++mi)                                        \
        _Pragma("unroll")                                                     \
            for (int nj = 0; nj < 2; ++nj)                                    \
                acc[mi][nj] = __builtin_amdgcn_mfma_f32_32x32x16_bf16(        \
                    fa0[mi], fb0[nj], acc[mi][nj], 0, 0, 0);                  \
        _Pragma("unroll")                                                     \
        for (int mi = 0; mi < 4; ++mi)                                        \
        _Pragma("unroll")                                                     \
            for (int nj = 0; nj < 2; ++nj)                                    \
                acc[mi][nj] = __builtin_amdgcn_mfma_f32_32x32x16_bf16(        \
                    fa1[mi], fb1[nj], acc[mi][nj], 0, 0, 0);                  \
        __builtin_amdgcn_s_setprio(0);                                        \
    } while (0)

    for (int u = 0; u < 10; ++u) {
        const int ks = u * 3;
        KSTEP(ks + 0, 0, 2, 1, "6");
        KSTEP(ks + 1, 1, 0, 1, "6");
        KSTEP(ks + 2, 2, 1, 1, "6");
    }
    KSTEP(30, 0, 2, 0, "6");
    KSTEP(31, 1, 0, 0, "0");
#undef KSTEP
#undef STAGE
}

// C/D register r -> row offset within the 32-row fragment
DI int crow(int r, int hi2) { return (r & 3) + 8 * (r >> 2) + 4 * hi2; }

// ---------------------------------------------------------------------------
// Kernel 2: fused QKV projection, 128x256 tiles. grid (64, 12): y = w*4 + nb.
// Q,K written (B,H,T,hd) bf16 (Q pre-scaled by 0.125); V written TRANSPOSED
// directly as VT (B,H,hd,T) -- k_vtrans eliminated (block covers full 128-t
// column spans, so L2 merges the 2B scattered stores).
// ---------------------------------------------------------------------------
__global__ __launch_bounds__(256, 2) void k_gemm_qkv(
    const unsigned short* __restrict__ xb,
    const unsigned short* __restrict__ wqb, const unsigned short* __restrict__ wkb,
    const unsigned short* __restrict__ wvb,
    unsigned short* __restrict__ Qo, unsigned short* __restrict__ Ko,
    unsigned short* __restrict__ VTo)
{
    extern __shared__ char smem[];
    const int bx = blockIdx.x, by = blockIdx.y;
    const int w = by >> 2, nb = by & 3;
    const unsigned short* Bw = (w == 0) ? wqb : ((w == 1) ? wkb : wvb);
    const float sc = (w == 0) ? 0.125f : 1.0f;

    f32x16 acc[4][2];
    gemm_core(xb, Bw, bx * 128, nb * 256, smem, acc);

    const int t = threadIdx.x, lane = t & 63;
    const int wc = t >> 6, l31 = lane & 31, hi2 = lane >> 5;
    const int h = nb * 4 + wc;               // head (wave-uniform)

    if (w < 2) {
        unsigned short* Ow = (w == 0) ? Qo : Ko;
#pragma unroll
        for (int mi = 0; mi < 4; ++mi)
#pragma unroll
            for (int r = 0; r < 16; ++r) {
                int grow = bx * 128 + mi * 32 + crow(r, hi2);
                int bi = grow >> 12, tt = grow & 4095;
                unsigned short* rowp =
                    Ow + ((long)(bi * 16 + h) * 4096 + tt) * 64;
#pragma unroll
                for (int nj = 0; nj < 2; ++nj)
                    rowp[nj * 32 + l31] = f2bf(acc[mi][nj][r] * sc);
            }
    } else {
#pragma unroll
        for (int mi = 0; mi < 4; ++mi)
#pragma unroll
            for (int r = 0; r < 16; ++r) {
                int grow = bx * 128 + mi * 32 + crow(r, hi2);
                int bi = grow >> 12, tt = grow & 4095;
#pragma unroll
                for (int nj = 0; nj < 2; ++nj) {
                    int d = nj * 32 + l31;
                    VTo[((long)(bi * 16 + h) * 64 + d) * 4096 + tt] =
                        f2bf(acc[mi][nj][r]);
                }
            }
    }
}

// ---------------------------------------------------------------------------
// Kernel 3: banded sliding-window attention (unchanged).
// ---------------------------------------------------------------------------
__global__ __launch_bounds__(256) void k_attn(
    const unsigned short* __restrict__ Q, const unsigned short* __restrict__ K,
    const unsigned short* __restrict__ VT, unsigned short* __restrict__ AO)
{
    __shared__ unsigned short Qs[4096];            // reused as P after prologue
    __shared__ unsigned short Ks[2][4096], Vs[2][4096];
    const int t = threadIdx.x, lane = t & 63, wid = t >> 6;
    const int kl = lane & 15, hi = lane >> 4;
    const int bid = blockIdx.x;
    const int sid = (bid & 7) * 256 + (bid >> 3);  // XCD-chunked (2048%8==0)
    const int i = sid & 63, bh = sid >> 6;
    const int b = bh >> 4, h = bh & 15;
    const char* qg = (const char*)(Q + ((long)bh * 4096 + i * 64) * 64);
    const char* kg = (const char*)(K + (long)bh * 4096 * 64);
    const char* vg = (const char*)(VT + (long)bh * 64 * 4096);

    const int c0 = t, c1 = t + 256;
    const int r0 = c0 >> 3, sw0 = ((c0 & 7) * 16) ^ ((r0 & 7) << 4);
    const int r1 = c1 >> 3, sw1 = ((c1 & 7) * 16) ^ ((r1 & 7) << 4);
    const char* kg0 = kg + r0 * 128 + sw0;    // + j*8192
    const char* kg1 = kg + r1 * 128 + sw1;
    const char* vg0 = vg + r0 * 8192 + sw0;   // + j*128
    const char* vg1 = vg + r1 * 8192 + sw1;

    const int j0 = (i >= 8) ? i - 8 : 0;

    gload_lds16(qg + r0 * 128 + sw0, (char*)Qs + c0 * 16);
    gload_lds16(qg + r1 * 128 + sw1, (char*)Qs + c1 * 16);
    gload_lds16(kg0 + j0 * 8192, (char*)Ks[0] + c0 * 16);
    gload_lds16(kg1 + j0 * 8192, (char*)Ks[0] + c1 * 16);
    gload_lds16(vg0 + j0 * 128,  (char*)Vs[0] + c0 * 16);
    gload_lds16(vg1 + j0 * 128,  (char*)Vs[0] + c1 * 16);
    __syncthreads();

    short8 aq[2];
    aq[0] = ldsfrag(Qs, wid * 16 + kl, hi * 16);
    aq[1] = ldsfrag(Qs, wid * 16 + kl, 64 + hi * 16);

    float lsum[4] = {0.f, 0.f, 0.f, 0.f};
    f32x4 o[4];
#pragma unroll
    for (int nt = 0; nt < 4; ++nt) o[nt] = f32x4{0.f, 0.f, 0.f, 0.f};

    const int qrow = wid * 16 + hi * 4;       // + r
    char* pw = (char*)Qs + wid * 2048;        // per-wave P region (own Q rows)

    for (int j = j0; j <= i; ++j) {
        const int buf = (j - j0) & 1;
        if (j < i) {                           // deferred prefetch of j+1
            const int nb = buf ^ 1;
            gload_lds16(kg0 + (j + 1) * 8192, (char*)Ks[nb] + c0 * 16);
            gload_lds16(kg1 + (j + 1) * 8192, (char*)Ks[nb] + c1 * 16);
            gload_lds16(vg0 + (j + 1) * 128,  (char*)Vs[nb] + c0 * 16);
            gload_lds16(vg1 + (j + 1) * 128,  (char*)Vs[nb] + c1 * 16);
        }

        f32x4 s[4];
#pragma unroll
        for (int nt = 0; nt < 4; ++nt) {
            s[nt] = f32x4{0.f, 0.f, 0.f, 0.f};
#pragma unroll
            for (int kk = 0; kk < 2; ++kk)
                s[nt] = __builtin_amdgcn_mfma_f32_16x16x32_bf16(
                    aq[kk], ldsfrag(Ks[buf], nt * 16 + kl, kk * 64 + hi * 16),
                    s[nt], 0, 0, 0);
        }

        if (j == i) {               // diagonal: valid iff key <= q
#pragma unroll
            for (int nt = 0; nt < 4; ++nt) {
                int key = nt * 16 + kl;
#pragma unroll
                for (int r = 0; r < 4; ++r)
                    if (key > qrow + r) s[nt][r] = -1e9f;
            }
        } else if (i - j == 8) {    // far edge: valid iff key > q
#pragma unroll
            for (int nt = 0; nt < 4; ++nt) {
                int key = nt * 16 + kl;
#pragma unroll
                for (int r = 0; r < 4; ++r)
                    if (key <= qrow + r) s[nt][r] = -1e9f;
            }
        }

#pragma unroll
        for (int nt = 0; nt < 4; ++nt)
#pragma unroll
            for (int r = 0; r < 4; ++r) {
                float p = __expf(s[nt][r]);
                s[nt][r] = p;
                lsum[r] += p;
            }

#pragma unroll
        for (int nt = 0; nt < 4; ++nt)
#pragma unroll
            for (int r = 0; r < 4; ++r) {
                int q = hi * 4 + r;
                int colb = (nt * 16 + kl) * 2;
                *(unsigned short*)(pw + q * 128 + (colb ^ ((q & 7) << 4))) =
                    f2bf(s[nt][r]);
            }

        short8 pa0 = ldsfrag(pw, kl, hi * 16);
        short8 pa1 = ldsfrag(pw, kl, 64 + hi * 16);
#pragma unroll
        for (int nt = 0; nt < 4; ++nt) {
            o[nt] = __builtin_amdgcn_mfma_f32_16x16x32_bf16(
                pa0, ldsfrag(Vs[buf], nt * 16 + kl, hi * 16), o[nt], 0, 0, 0);
            o[nt] = __builtin_amdgcn_mfma_f32_16x16x32_bf16(
                pa1, ldsfrag(Vs[buf], nt * 16 + kl, 64 + hi * 16), o[nt], 0, 0, 0);
        }

        __syncthreads();
    }

#pragma unroll
    for (int d = 1; d < 16; d <<= 1)
#pragma unroll
        for (int r = 0; r < 4; ++r) lsum[r] += __shfl_xor(lsum[r], d);

    float inv[4];
#pragma unroll
    for (int r = 0; r < 4; ++r) inv[r] = 1.0f / lsum[r];
#pragma unroll
    for (int r = 0; r < 4; ++r) {
        int tt = i * 64 + wid * 16 + hi * 4 + r;
        unsigned short* rowp = AO + ((long)(b * 4096 + tt)) * 1024 + h * 64;
#pragma unroll
        for (int nt = 0; nt < 4; ++nt)
            rowp[nt * 16 + kl] = f2bf(o[nt][r] * inv[r]);
    }
}

// ---------------------------------------------------------------------------
// Kernel 4: output projection (128x256 tiles) -> fp32 d_out. grid (64, 4).
// ---------------------------------------------------------------------------
__global__ __launch_bounds__(256, 2) void k_gemm_out(
    const unsigned short* __restrict__ AO, const unsigned short* __restrict__ wob,
    float* __restrict__ out)
{
    extern __shared__ char smem[];
    const int bx = blockIdx.x, nb = blockIdx.y;
    f32x16 acc[4][2];
    gemm_core(AO, wob, bx * 128, nb * 256, smem, acc);

    const int t = threadIdx.x, lane = t & 63;
    const int wc = t >> 6, l31 = lane & 31, hi2 = lane >> 5;
#pragma unroll
    for (int mi = 0; mi < 4; ++mi)
#pragma unroll
        for (int r = 0; r < 16; ++r) {
            int grow = bx * 128 + mi * 32 + crow(r, hi2);
            float* rowp = out + (long)grow * 1024 + nb * 256 + wc * 64;
#pragma unroll
            for (int nj = 0; nj < 2; ++nj)
                rowp[nj * 32 + l31] = acc[mi][nj][r];
        }
}

// ---------------------------------------------------------------------------
extern "C" void kernel_launch(void* const* d_in, const int* in_sizes, int n_in,
                              void* d_out, int out_size, void* d_ws, size_t ws_size,
                              hipStream_t stream) {
    const float* x  = (const float*)d_in[0];
    const float* wq = (const float*)d_in[1];
    const float* wk = (const float*)d_in[2];
    const float* wv = (const float*)d_in[3];
    const float* wo = (const float*)d_in[4];

    char* ws = (char*)d_ws;
    const size_t MB = 1024 * 1024;
    unsigned short* xb  = (unsigned short*)(ws);            // 16 MB, reused as AO
    unsigned short* wqb = (unsigned short*)(ws + 16 * MB);  // 2 MB
    unsigned short* wkb = (unsigned short*)(ws + 18 * MB);
    unsigned short* wvb = (unsigned short*)(ws + 20 * MB);
    unsigned short* wob = (unsigned short*)(ws + 22 * MB);
    unsigned short* Qp  = (unsigned short*)(ws + 24 * MB);  // 16 MB each
    unsigned short* Kp  = (unsigned short*)(ws + 40 * MB);
    unsigned short* VTp = (unsigned short*)(ws + 72 * MB);  // end 88 MB
    unsigned short* AOp = xb;  // x no longer needed after QKV GEMM

    hipFuncSetAttribute((const void*)k_gemm_qkv,
                        hipFuncAttributeMaxDynamicSharedMemorySize, 73728);
    hipFuncSetAttribute((const void*)k_gemm_out,
                        hipFuncAttributeMaxDynamicSharedMemorySize, 73728);

    dim3 blk(256);
    k_cvt<<<12288, blk, 0, stream>>>(x, wq, wk, wv, wo,
                                     xb, wqb, wkb, wvb, wob);
    k_gemm_qkv<<<dim3(64, 12), 256, 73728, stream>>>(xb, wqb, wkb, wvb,
                                                     Qp, Kp, VTp);
    k_attn<<<2048, blk, 0, stream>>>(Qp, Kp, VTp, AOp);
    k_gemm_out<<<dim3(64, 4), 256, 73728, stream>>>(AOp, wob, (float*)d_out);
}

// Round 9
// 138.414 us; speedup vs baseline: 1.0777x; 1.0777x over previous
//
#include <hip/hip_runtime.h>

#define DI static __device__ __forceinline__

typedef __attribute__((ext_vector_type(8))) short short8;  // 8 bf16 in 4 VGPRs
typedef __attribute__((ext_vector_type(4))) float f32x4;

// fp32 -> bf16 round-to-nearest-even
DI unsigned short f2bf(float f) {
    union { float f; unsigned int u; } v; v.f = f;
    unsigned int r = v.u + 0x7FFFu + ((v.u >> 16) & 1u);
    return (unsigned short)(r >> 16);
}

// async global->LDS, 16B per lane. LDS dest must be wave-uniform base + lane*16.
DI void gload_lds16(const void* g, void* l) {
    __builtin_amdgcn_global_load_lds(
        (const __attribute__((address_space(1))) void*)g,
        (__attribute__((address_space(3))) void*)l, 16, 0, 0);
}

// swizzled LDS fragment read for 128B-row tiles (attention)
DI short8 ldsfrag(const void* base, int row, int bytecol) {
    return *(const short8*)((const char*)base + row * 128 + (bytecol ^ ((row & 7) << 4)));
}

// ---------------------------------------------------------------------------
// Kernel 1: fp32 -> bf16 conversion, flat 1D grid (x 8M elems, 4 x 1M weights)
// ---------------------------------------------------------------------------
__global__ __launch_bounds__(256) void k_cvt(
    const float* __restrict__ x, const float* __restrict__ wq,
    const float* __restrict__ wk, const float* __restrict__ wv,
    const float* __restrict__ wo,
    unsigned short* __restrict__ xb, unsigned short* __restrict__ wqb,
    unsigned short* __restrict__ wkb, unsigned short* __restrict__ wvb,
    unsigned short* __restrict__ wob)
{
    int idx = (blockIdx.x * 256 + threadIdx.x) * 4;   // < 12582912
    const float* src; unsigned short* dst; int off;
    if (idx < 8388608) {
        src = x; dst = xb; off = idx;
    } else {
        int rel = idx - 8388608;
        int sel = rel >> 20;
        off = rel & 1048575;
        switch (sel) {
            case 0:  src = wq; dst = wqb; break;
            case 1:  src = wk; dst = wkb; break;
            case 2:  src = wv; dst = wvb; break;
            default: src = wo; dst = wob; break;
        }
    }
    float4 v = *(const float4*)(src + off);
    unsigned long long o = (unsigned long long)f2bf(v.x)
        | ((unsigned long long)f2bf(v.y) << 16)
        | ((unsigned long long)f2bf(v.z) << 32)
        | ((unsigned long long)f2bf(v.w) << 48);
    *(unsigned long long*)(dst + off) = o;
}

// ---------------------------------------------------------------------------
// 128x256 GEMM core, BK=32, K=1024. C[i][j] = sum_k A[i][k]*B[j][k] (NT).
// 8 waves (2M x 4N), per-wave C = 64x64 = 4x4 16x16x32 frags.
// 3 LDS buffers x (A 8KB + B 16KB) = 72KB -> 2 blocks/CU co-resident.
// Counted-vmcnt pipeline (R5/R6-proven, best measured: 57.4us qkv, 0 confl):
//   body ks: vmcnt(3) [tile ks landed; ks+1 in flight] -> s_barrier ->
//            issue tile ks+2 into buf[(ks+2)%3] -> 8 ds_read_b128 -> 16 MFMA.
// LDS rows are 64B (32 bf16); slot swizzle slot^=(row>>1)&3 on pre-swizzled
// global source AND fragment read (R3/R5/R6: conflicts == 0).
// ---------------------------------------------------------------------------
DI void gemm_core(const unsigned short* __restrict__ Ag,
                  const unsigned short* __restrict__ Bg,
                  int m0, int n0, char* smem, f32x4 acc[4][4])
{
    const int t = threadIdx.x, lane = t & 63;
    const int wid = t >> 6, wr = wid >> 2, wc = wid & 3;
    const int kl = lane & 15, hi = lane >> 4;

#pragma unroll
    for (int m = 0; m < 4; ++m)
#pragma unroll
        for (int n = 0; n < 4; ++n)
            acc[m][n] = f32x4{0.f, 0.f, 0.f, 0.f};

    // staging: A = 512 chunks of 16B (1/thread), B = 1024 chunks (2/thread)
    // chunk c: row = c>>2 (64B rows), slot = c&3, src slot = slot ^ ((row>>1)&3)
    const int ca  = t,       ra  = ca  >> 2, sa  = ((ca  & 3) ^ ((ra  >> 1) & 3)) * 8;
    const int cb0 = t,       rb0 = cb0 >> 2, sb0 = ((cb0 & 3) ^ ((rb0 >> 1) & 3)) * 8;
    const int cb1 = t + 512, rb1 = cb1 >> 2, sb1 = ((cb1 & 3) ^ ((rb1 >> 1) & 3)) * 8;
    const unsigned short* pa  = Ag + (long)(m0 + ra)  * 1024 + sa;
    const unsigned short* pb0 = Bg + (long)(n0 + rb0) * 1024 + sb0;
    const unsigned short* pb1 = Bg + (long)(n0 + rb1) * 1024 + sb1;

#define STAGE(TILE, BUF) do {                                          \
        char* _sb = smem + (BUF) * 24576;                              \
        gload_lds16(pa  + (TILE) * 32, _sb + ca * 16);                 \
        gload_lds16(pb0 + (TILE) * 32, _sb + 8192 + cb0 * 16);         \
        gload_lds16(pb1 + (TILE) * 32, _sb + 8192 + cb1 * 16);         \
    } while (0)

    // prologue: tiles 0 and 1 in flight
    STAGE(0, 0);
    STAGE(1, 1);

    // fragment read offsets (swizzle key (kl>>1)&3; row = base16 + kl)
    const int swz = ((hi ^ ((kl >> 1) & 3)) << 4);
    const int aoff = (wr * 64 + kl) * 64 + swz;           // + m*1024
    const int boff = 8192 + (wc * 64 + kl) * 64 + swz;    // + n*1024

#define KSTEP(KS, CUR, PRE, ISSUE, VM) do {                                   \
        asm volatile("s_waitcnt vmcnt(" VM ")" ::: "memory");                 \
        __builtin_amdgcn_s_barrier();                                         \
        __builtin_amdgcn_sched_barrier(0);                                    \
        if (ISSUE) STAGE((KS) + 2, PRE);                                      \
        const char* _ab = smem + (CUR) * 24576 + aoff;                        \
        const char* _bb = smem + (CUR) * 24576 + boff;                        \
        short8 _fa[4], _fb[4];                                                \
        _Pragma("unroll")                                                     \
        for (int m = 0; m < 4; ++m) _fa[m] = *(const short8*)(_ab + m * 1024);\
        _Pragma("unroll")                                                     \
        for (int n = 0; n < 4; ++n) _fb[n] = *(const short8*)(_bb + n * 1024);\
        __builtin_amdgcn_s_setprio(1);                                        \
        _Pragma("unroll")                                                     \
        for (int m = 0; m < 4; ++m)                                           \
        _Pragma("unroll")                                                     \
            for (int n = 0; n < 4; ++n)                                       \
                acc[m][n] = __builtin_amdgcn_mfma_f32_16x16x32_bf16(          \
                    _fa[m], _fb[n], acc[m][n], 0, 0, 0);                      \
        __builtin_amdgcn_s_setprio(0);                                        \
    } while (0)

    for (int u = 0; u < 10; ++u) {
        const int ks = u * 3;
        KSTEP(ks + 0, 0, 2, 1, "3");
        KSTEP(ks + 1, 1, 0, 1, "3");
        KSTEP(ks + 2, 2, 1, 1, "3");
    }
    KSTEP(30, 0, 2, 0, "3");
    KSTEP(31, 1, 0, 0, "0");
#undef KSTEP
#undef STAGE
}

// ---------------------------------------------------------------------------
// Kernel 2: fused QKV projection, 128x256 tiles. grid (64, 12): y = w*4 + nb.
// Q,K written (B,H,T,hd) bf16 (Q pre-scaled by 0.125); V written TRANSPOSED
// directly as VT (B,H,hd,T) -- no separate transpose kernel (R8: WRITE_SIZE
// unchanged at 48MB, L2 merges the 2B scattered stores).
// ---------------------------------------------------------------------------
__global__ __launch_bounds__(512, 4) void k_gemm_qkv(
    const unsigned short* __restrict__ xb,
    const unsigned short* __restrict__ wqb, const unsigned short* __restrict__ wkb,
    const unsigned short* __restrict__ wvb,
    unsigned short* __restrict__ Qo, unsigned short* __restrict__ Ko,
    unsigned short* __restrict__ VTo)
{
    extern __shared__ char smem[];
    const int bx = blockIdx.x, by = blockIdx.y;
    const int w = by >> 2, nb = by & 3;
    const unsigned short* Bw = (w == 0) ? wqb : ((w == 1) ? wkb : wvb);
    const float sc = (w == 0) ? 0.125f : 1.0f;

    f32x4 acc[4][4];
    gemm_core(xb, Bw, bx * 128, nb * 256, smem, acc);

    const int t = threadIdx.x, lane = t & 63, wid = t >> 6;
    const int wr = wid >> 2, wc = wid & 3, kl = lane & 15, hi = lane >> 4;
    const int h = nb * 4 + wc;       // head (wave-uniform)

    if (w < 2) {
        unsigned short* Ow = (w == 0) ? Qo : Ko;
#pragma unroll
        for (int m = 0; m < 4; ++m)
#pragma unroll
            for (int r = 0; r < 4; ++r) {
                int grow = bx * 128 + wr * 64 + m * 16 + hi * 4 + r;
                int bi = grow >> 12, tt = grow & 4095;
                unsigned short* rowp = Ow + ((long)(bi * 16 + h) * 4096 + tt) * 64;
#pragma unroll
                for (int n = 0; n < 4; ++n)
                    rowp[n * 16 + kl] = f2bf(acc[m][n][r] * sc);
            }
    } else {
#pragma unroll
        for (int m = 0; m < 4; ++m)
#pragma unroll
            for (int r = 0; r < 4; ++r) {
                int grow = bx * 128 + wr * 64 + m * 16 + hi * 4 + r;
                int bi = grow >> 12, tt = grow & 4095;
                unsigned short* hb = VTo + (long)(bi * 16 + h) * 262144;
#pragma unroll
                for (int n = 0; n < 4; ++n) {
                    int d = n * 16 + kl;
                    hb[(long)d * 4096 + tt] = f2bf(acc[m][n][r]);
                }
            }
    }
}

// ---------------------------------------------------------------------------
// Kernel 3: banded sliding-window attention (unchanged since R2).
// ---------------------------------------------------------------------------
__global__ __launch_bounds__(256) void k_attn(
    const unsigned short* __restrict__ Q, const unsigned short* __restrict__ K,
    const unsigned short* __restrict__ VT, unsigned short* __restrict__ AO)
{
    __shared__ unsigned short Qs[4096];            // reused as P after prologue
    __shared__ unsigned short Ks[2][4096], Vs[2][4096];
    const int t = threadIdx.x, lane = t & 63, wid = t >> 6;
    const int kl = lane & 15, hi = lane >> 4;
    const int bid = blockIdx.x;
    const int sid = (bid & 7) * 256 + (bid >> 3);  // XCD-chunked (2048%8==0)
    const int i = sid & 63, bh = sid >> 6;
    const int b = bh >> 4, h = bh & 15;
    const char* qg = (const char*)(Q + ((long)bh * 4096 + i * 64) * 64);
    const char* kg = (const char*)(K + (long)bh * 4096 * 64);
    const char* vg = (const char*)(VT + (long)bh * 64 * 4096);

    const int c0 = t, c1 = t + 256;
    const int r0 = c0 >> 3, sw0 = ((c0 & 7) * 16) ^ ((r0 & 7) << 4);
    const int r1 = c1 >> 3, sw1 = ((c1 & 7) * 16) ^ ((r1 & 7) << 4);
    const char* kg0 = kg + r0 * 128 + sw0;    // + j*8192
    const char* kg1 = kg + r1 * 128 + sw1;
    const char* vg0 = vg + r0 * 8192 + sw0;   // + j*128
    const char* vg1 = vg + r1 * 8192 + sw1;

    const int j0 = (i >= 8) ? i - 8 : 0;

    gload_lds16(qg + r0 * 128 + sw0, (char*)Qs + c0 * 16);
    gload_lds16(qg + r1 * 128 + sw1, (char*)Qs + c1 * 16);
    gload_lds16(kg0 + j0 * 8192, (char*)Ks[0] + c0 * 16);
    gload_lds16(kg1 + j0 * 8192, (char*)Ks[0] + c1 * 16);
    gload_lds16(vg0 + j0 * 128,  (char*)Vs[0] + c0 * 16);
    gload_lds16(vg1 + j0 * 128,  (char*)Vs[0] + c1 * 16);
    __syncthreads();

    short8 aq[2];
    aq[0] = ldsfrag(Qs, wid * 16 + kl, hi * 16);
    aq[1] = ldsfrag(Qs, wid * 16 + kl, 64 + hi * 16);

    float lsum[4] = {0.f, 0.f, 0.f, 0.f};
    f32x4 o[4];
#pragma unroll
    for (int nt = 0; nt < 4; ++nt) o[nt] = f32x4{0.f, 0.f, 0.f, 0.f};

    const int qrow = wid * 16 + hi * 4;       // + r
    char* pw = (char*)Qs + wid * 2048;        // per-wave P region (own Q rows)

    for (int j = j0; j <= i; ++j) {
        const int buf = (j - j0) & 1;
        if (j < i) {                           // deferred prefetch of j+1
            const int nb = buf ^ 1;
            gload_lds16(kg0 + (j + 1) * 8192, (char*)Ks[nb] + c0 * 16);
            gload_lds16(kg1 + (j + 1) * 8192, (char*)Ks[nb] + c1 * 16);
            gload_lds16(vg0 + (j + 1) * 128,  (char*)Vs[nb] + c0 * 16);
            gload_lds16(vg1 + (j + 1) * 128,  (char*)Vs[nb] + c1 * 16);
        }

        f32x4 s[4];
#pragma unroll
        for (int nt = 0; nt < 4; ++nt) {
            s[nt] = f32x4{0.f, 0.f, 0.f, 0.f};
#pragma unroll
            for (int kk = 0; kk < 2; ++kk)
                s[nt] = __builtin_amdgcn_mfma_f32_16x16x32_bf16(
                    aq[kk], ldsfrag(Ks[buf], nt * 16 + kl, kk * 64 + hi * 16),
                    s[nt], 0, 0, 0);
        }

        if (j == i) {               // diagonal: valid iff key <= q
#pragma unroll
            for (int nt = 0; nt < 4; ++nt) {
                int key = nt * 16 + kl;
#pragma unroll
                for (int r = 0; r < 4; ++r)
                    if (key > qrow + r) s[nt][r] = -1e9f;
            }
        } else if (i - j == 8) {    // far edge: valid iff key > q
#pragma unroll
            for (int nt = 0; nt < 4; ++nt) {
                int key = nt * 16 + kl;
#pragma unroll
                for (int r = 0; r < 4; ++r)
                    if (key <= qrow + r) s[nt][r] = -1e9f;
            }
        }

#pragma unroll
        for (int nt = 0; nt < 4; ++nt)
#pragma unroll
            for (int r = 0; r < 4; ++r) {
                float p = __expf(s[nt][r]);
                s[nt][r] = p;
                lsum[r] += p;
            }

#pragma unroll
        for (int nt = 0; nt < 4; ++nt)
#pragma unroll
            for (int r = 0; r < 4; ++r) {
                int q = hi * 4 + r;
                int colb = (nt * 16 + kl) * 2;
                *(unsigned short*)(pw + q * 128 + (colb ^ ((q & 7) << 4))) =
                    f2bf(s[nt][r]);
            }

        short8 pa0 = ldsfrag(pw, kl, hi * 16);
        short8 pa1 = ldsfrag(pw, kl, 64 + hi * 16);
#pragma unroll
        for (int nt = 0; nt < 4; ++nt) {
            o[nt] = __builtin_amdgcn_mfma_f32_16x16x32_bf16(
                pa0, ldsfrag(Vs[buf], nt * 16 + kl, hi * 16), o[nt], 0, 0, 0);
            o[nt] = __builtin_amdgcn_mfma_f32_16x16x32_bf16(
                pa1, ldsfrag(Vs[buf], nt * 16 + kl, 64 + hi * 16), o[nt], 0, 0, 0);
        }

        __syncthreads();
    }

#pragma unroll
    for (int d = 1; d < 16; d <<= 1)
#pragma unroll
        for (int r = 0; r < 4; ++r) lsum[r] += __shfl_xor(lsum[r], d);

    float inv[4];
#pragma unroll
    for (int r = 0; r < 4; ++r) inv[r] = 1.0f / lsum[r];
#pragma unroll
    for (int r = 0; r < 4; ++r) {
        int tt = i * 64 + wid * 16 + hi * 4 + r;
        unsigned short* rowp = AO + ((long)(b * 4096 + tt)) * 1024 + h * 64;
#pragma unroll
        for (int nt = 0; nt < 4; ++nt)
            rowp[nt * 16 + kl] = f2bf(o[nt][r] * inv[r]);
    }
}

// ---------------------------------------------------------------------------
// Kernel 4: output projection (128x256 tiles) -> fp32 d_out. grid (64, 4).
// ---------------------------------------------------------------------------
__global__ __launch_bounds__(512, 4) void k_gemm_out(
    const unsigned short* __restrict__ AO, const unsigned short* __restrict__ wob,
    float* __restrict__ out)
{
    extern __shared__ char smem[];
    const int bx = blockIdx.x, nb = blockIdx.y;
    f32x4 acc[4][4];
    gemm_core(AO, wob, bx * 128, nb * 256, smem, acc);

    const int t = threadIdx.x, lane = t & 63, wid = t >> 6;
    const int wr = wid >> 2, wc = wid & 3, kl = lane & 15, hi = lane >> 4;
#pragma unroll
    for (int m = 0; m < 4; ++m)
#pragma unroll
        for (int r = 0; r < 4; ++r) {
            int grow = bx * 128 + wr * 64 + m * 16 + hi * 4 + r;
            float* rowp = out + (long)grow * 1024 + nb * 256 + wc * 64;
#pragma unroll
            for (int n = 0; n < 4; ++n)
                rowp[n * 16 + kl] = acc[m][n][r];
        }
}

// ---------------------------------------------------------------------------
extern "C" void kernel_launch(void* const* d_in, const int* in_sizes, int n_in,
                              void* d_out, int out_size, void* d_ws, size_t ws_size,
                              hipStream_t stream) {
    const float* x  = (const float*)d_in[0];
    const float* wq = (const float*)d_in[1];
    const float* wk = (const float*)d_in[2];
    const float* wv = (const float*)d_in[3];
    const float* wo = (const float*)d_in[4];

    char* ws = (char*)d_ws;
    const size_t MB = 1024 * 1024;
    unsigned short* xb  = (unsigned short*)(ws);            // 16 MB, reused as AO
    unsigned short* wqb = (unsigned short*)(ws + 16 * MB);  // 2 MB
    unsigned short* wkb = (unsigned short*)(ws + 18 * MB);
    unsigned short* wvb = (unsigned short*)(ws + 20 * MB);
    unsigned short* wob = (unsigned short*)(ws + 22 * MB);
    unsigned short* Qp  = (unsigned short*)(ws + 24 * MB);  // 16 MB each
    unsigned short* Kp  = (unsigned short*)(ws + 40 * MB);
    unsigned short* VTp = (unsigned short*)(ws + 56 * MB);  // end 72 MB
    unsigned short* AOp = xb;  // x no longer needed after QKV GEMM

    hipFuncSetAttribute((const void*)k_gemm_qkv,
                        hipFuncAttributeMaxDynamicSharedMemorySize, 73728);
    hipFuncSetAttribute((const void*)k_gemm_out,
                        hipFuncAttributeMaxDynamicSharedMemorySize, 73728);

    dim3 blk(256);
    k_cvt<<<12288, blk, 0, stream>>>(x, wq, wk, wv, wo,
                                     xb, wqb, wkb, wvb, wob);
    k_gemm_qkv<<<dim3(64, 12), 512, 73728, stream>>>(xb, wqb, wkb, wvb,
                                                     Qp, Kp, VTp);
    k_attn<<<2048, blk, 0, stream>>>(Qp, Kp, VTp, AOp);
    k_gemm_out<<<dim3(64, 4), 512, 73728, stream>>>(AOp, wob, (float*)d_out);
}

// Round 10
// 136.505 us; speedup vs baseline: 1.0927x; 1.0140x over previous
//
#include <hip/hip_runtime.h>

#define DI static __device__ __forceinline__

typedef __attribute__((ext_vector_type(8))) short short8;  // 8 bf16 in 4 VGPRs
typedef __attribute__((ext_vector_type(4))) float f32x4;

// fp32 -> bf16 round-to-nearest-even
DI unsigned short f2bf(float f) {
    union { float f; unsigned int u; } v; v.f = f;
    unsigned int r = v.u + 0x7FFFu + ((v.u >> 16) & 1u);
    return (unsigned short)(r >> 16);
}

// async global->LDS, 16B per lane. LDS dest must be wave-uniform base + lane*16.
DI void gload_lds16(const void* g, void* l) {
    __builtin_amdgcn_global_load_lds(
        (const __attribute__((address_space(1))) void*)g,
        (__attribute__((address_space(3))) void*)l, 16, 0, 0);
}

// swizzled LDS fragment read for 128B-row tiles (attention)
DI short8 ldsfrag(const void* base, int row, int bytecol) {
    return *(const short8*)((const char*)base + row * 128 + (bytecol ^ ((row & 7) << 4)));
}

// ---------------------------------------------------------------------------
// Kernel 1: fp32 -> bf16 conversion, flat 1D grid (x 8M elems, 4 x 1M weights)
// ---------------------------------------------------------------------------
__global__ __launch_bounds__(256) void k_cvt(
    const float* __restrict__ x, const float* __restrict__ wq,
    const float* __restrict__ wk, const float* __restrict__ wv,
    const float* __restrict__ wo,
    unsigned short* __restrict__ xb, unsigned short* __restrict__ wqb,
    unsigned short* __restrict__ wkb, unsigned short* __restrict__ wvb,
    unsigned short* __restrict__ wob)
{
    int idx = (blockIdx.x * 256 + threadIdx.x) * 4;   // < 12582912
    const float* src; unsigned short* dst; int off;
    if (idx < 8388608) {
        src = x; dst = xb; off = idx;
    } else {
        int rel = idx - 8388608;
        int sel = rel >> 20;
        off = rel & 1048575;
        switch (sel) {
            case 0:  src = wq; dst = wqb; break;
            case 1:  src = wk; dst = wkb; break;
            case 2:  src = wv; dst = wvb; break;
            default: src = wo; dst = wob; break;
        }
    }
    float4 v = *(const float4*)(src + off);
    unsigned long long o = (unsigned long long)f2bf(v.x)
        | ((unsigned long long)f2bf(v.y) << 16)
        | ((unsigned long long)f2bf(v.z) << 32)
        | ((unsigned long long)f2bf(v.w) << 48);
    *(unsigned long long*)(dst + off) = o;
}

// ---------------------------------------------------------------------------
// 128x256 GEMM core (R6/R9-proven, 888 TF, 0 conflicts): BK=32, K=1024,
// 8 waves (2M x 4N), 3 LDS bufs x 24KB = 72KB, counted-vmcnt(3) pipeline.
// ---------------------------------------------------------------------------
DI void gemm_core(const unsigned short* __restrict__ Ag,
                  const unsigned short* __restrict__ Bg,
                  int m0, int n0, char* smem, f32x4 acc[4][4])
{
    const int t = threadIdx.x, lane = t & 63;
    const int wid = t >> 6, wr = wid >> 2, wc = wid & 3;
    const int kl = lane & 15, hi = lane >> 4;

#pragma unroll
    for (int m = 0; m < 4; ++m)
#pragma unroll
        for (int n = 0; n < 4; ++n)
            acc[m][n] = f32x4{0.f, 0.f, 0.f, 0.f};

    const int ca  = t,       ra  = ca  >> 2, sa  = ((ca  & 3) ^ ((ra  >> 1) & 3)) * 8;
    const int cb0 = t,       rb0 = cb0 >> 2, sb0 = ((cb0 & 3) ^ ((rb0 >> 1) & 3)) * 8;
    const int cb1 = t + 512, rb1 = cb1 >> 2, sb1 = ((cb1 & 3) ^ ((rb1 >> 1) & 3)) * 8;
    const unsigned short* pa  = Ag + (long)(m0 + ra)  * 1024 + sa;
    const unsigned short* pb0 = Bg + (long)(n0 + rb0) * 1024 + sb0;
    const unsigned short* pb1 = Bg + (long)(n0 + rb1) * 1024 + sb1;

#define STAGE(TILE, BUF) do {                                          \
        char* _sb = smem + (BUF) * 24576;                              \
        gload_lds16(pa  + (TILE) * 32, _sb + ca * 16);                 \
        gload_lds16(pb0 + (TILE) * 32, _sb + 8192 + cb0 * 16);         \
        gload_lds16(pb1 + (TILE) * 32, _sb + 8192 + cb1 * 16);         \
    } while (0)

    STAGE(0, 0);
    STAGE(1, 1);

    const int swz = ((hi ^ ((kl >> 1) & 3)) << 4);
    const int aoff = (wr * 64 + kl) * 64 + swz;           // + m*1024
    const int boff = 8192 + (wc * 64 + kl) * 64 + swz;    // + n*1024

#define KSTEP(KS, CUR, PRE, ISSUE, VM) do {                                   \
        asm volatile("s_waitcnt vmcnt(" VM ")" ::: "memory");                 \
        __builtin_amdgcn_s_barrier();                                         \
        __builtin_amdgcn_sched_barrier(0);                                    \
        if (ISSUE) STAGE((KS) + 2, PRE);                                      \
        const char* _ab = smem + (CUR) * 24576 + aoff;                        \
        const char* _bb = smem + (CUR) * 24576 + boff;                        \
        short8 _fa[4], _fb[4];                                                \
        _Pragma("unroll")                                                     \
        for (int m = 0; m < 4; ++m) _fa[m] = *(const short8*)(_ab + m * 1024);\
        _Pragma("unroll")                                                     \
        for (int n = 0; n < 4; ++n) _fb[n] = *(const short8*)(_bb + n * 1024);\
        __builtin_amdgcn_s_setprio(1);                                        \
        _Pragma("unroll")                                                     \
        for (int m = 0; m < 4; ++m)                                           \
        _Pragma("unroll")                                                     \
            for (int n = 0; n < 4; ++n)                                       \
                acc[m][n] = __builtin_amdgcn_mfma_f32_16x16x32_bf16(          \
                    _fa[m], _fb[n], acc[m][n], 0, 0, 0);                      \
        __builtin_amdgcn_s_setprio(0);                                        \
    } while (0)

    for (int u = 0; u < 10; ++u) {
        const int ks = u * 3;
        KSTEP(ks + 0, 0, 2, 1, "3");
        KSTEP(ks + 1, 1, 0, 1, "3");
        KSTEP(ks + 2, 2, 1, 1, "3");
    }
    KSTEP(30, 0, 2, 0, "3");
    KSTEP(31, 1, 0, 0, "0");
#undef KSTEP
#undef STAGE
}

// ---------------------------------------------------------------------------
// 128x128 GEMM core, 4 waves (2M x 2N), same counted-vmcnt(4) schedule.
// 3 LDS bufs x 16KB = 48KB -> 3 blocks/CU; used by k_gemm_out so its 512
// blocks get >=2 co-resident blocks/CU (R5 lesson: no-partner costs ~25%).
// ---------------------------------------------------------------------------
DI void gemm_core128(const unsigned short* __restrict__ Ag,
                     const unsigned short* __restrict__ Bg,
                     int m0, int n0, char* smem, f32x4 acc[4][4])
{
    const int t = threadIdx.x, lane = t & 63;
    const int wid = t >> 6, wr = wid >> 1, wc = wid & 1;
    const int kl = lane & 15, hi = lane >> 4;

#pragma unroll
    for (int m = 0; m < 4; ++m)
#pragma unroll
        for (int n = 0; n < 4; ++n)
            acc[m][n] = f32x4{0.f, 0.f, 0.f, 0.f};

    const int ca0 = t,       ra0 = ca0 >> 2, sa0 = ((ca0 & 3) ^ ((ra0 >> 1) & 3)) * 8;
    const int ca1 = t + 256, ra1 = ca1 >> 2, sa1 = ((ca1 & 3) ^ ((ra1 >> 1) & 3)) * 8;
    const unsigned short* pa0 = Ag + (long)(m0 + ra0) * 1024 + sa0;
    const unsigned short* pa1 = Ag + (long)(m0 + ra1) * 1024 + sa1;
    const unsigned short* pb0 = Bg + (long)(n0 + ra0) * 1024 + sa0;
    const unsigned short* pb1 = Bg + (long)(n0 + ra1) * 1024 + sa1;

#define STAGE(TILE, BUF) do {                                          \
        char* _sb = smem + (BUF) * 16384;                              \
        gload_lds16(pa0 + (TILE) * 32, _sb + ca0 * 16);                \
        gload_lds16(pa1 + (TILE) * 32, _sb + ca1 * 16);                \
        gload_lds16(pb0 + (TILE) * 32, _sb + 8192 + ca0 * 16);         \
        gload_lds16(pb1 + (TILE) * 32, _sb + 8192 + ca1 * 16);         \
    } while (0)

    STAGE(0, 0);
    STAGE(1, 1);

    const int swz = ((hi ^ ((kl >> 1) & 3)) << 4);
    const int aoff = (wr * 64 + kl) * 64 + swz;           // + m*1024
    const int boff = 8192 + (wc * 64 + kl) * 64 + swz;    // + n*1024

#define KSTEP(KS, CUR, PRE, ISSUE, VM) do {                                   \
        asm volatile("s_waitcnt vmcnt(" VM ")" ::: "memory");                 \
        __builtin_amdgcn_s_barrier();                                         \
        __builtin_amdgcn_sched_barrier(0);                                    \
        if (ISSUE) STAGE((KS) + 2, PRE);                                      \
        const char* _ab = smem + (CUR) * 16384 + aoff;                        \
        const char* _bb = smem + (CUR) * 16384 + boff;                        \
        short8 _fa[4], _fb[4];                                                \
        _Pragma("unroll")                                                     \
        for (int m = 0; m < 4; ++m) _fa[m] = *(const short8*)(_ab + m * 1024);\
        _Pragma("unroll")                                                     \
        for (int n = 0; n < 4; ++n) _fb[n] = *(const short8*)(_bb + n * 1024);\
        __builtin_amdgcn_s_setprio(1);                                        \
        _Pragma("unroll")                                                     \
        for (int m = 0; m < 4; ++m)                                           \
        _Pragma("unroll")                                                     \
            for (int n = 0; n < 4; ++n)                                       \
                acc[m][n] = __builtin_amdgcn_mfma_f32_16x16x32_bf16(          \
                    _fa[m], _fb[n], acc[m][n], 0, 0, 0);                      \
        __builtin_amdgcn_s_setprio(0);                                        \
    } while (0)

    for (int u = 0; u < 10; ++u) {
        const int ks = u * 3;
        KSTEP(ks + 0, 0, 2, 1, "4");
        KSTEP(ks + 1, 1, 0, 1, "4");
        KSTEP(ks + 2, 2, 1, 1, "4");
    }
    KSTEP(30, 0, 2, 0, "4");
    KSTEP(31, 1, 0, 0, "0");
#undef KSTEP
#undef STAGE
}

// ---------------------------------------------------------------------------
// Kernel 2: fused QKV projection (unchanged from R9). Q scale now includes
// log2(e) so attention can use exp2 directly: 0.125 * 1.44269504.
// ---------------------------------------------------------------------------
__global__ __launch_bounds__(512, 4) void k_gemm_qkv(
    const unsigned short* __restrict__ xb,
    const unsigned short* __restrict__ wqb, const unsigned short* __restrict__ wkb,
    const unsigned short* __restrict__ wvb,
    unsigned short* __restrict__ Qo, unsigned short* __restrict__ Ko,
    unsigned short* __restrict__ VTo)
{
    extern __shared__ char smem[];
    const int bx = blockIdx.x, by = blockIdx.y;
    const int w = by >> 2, nb = by & 3;
    const unsigned short* Bw = (w == 0) ? wqb : ((w == 1) ? wkb : wvb);
    const float sc = (w == 0) ? 0.18033688011112042f : 1.0f;  // 0.125*log2(e)

    f32x4 acc[4][4];
    gemm_core(xb, Bw, bx * 128, nb * 256, smem, acc);

    const int t = threadIdx.x, lane = t & 63, wid = t >> 6;
    const int wr = wid >> 2, wc = wid & 3, kl = lane & 15, hi = lane >> 4;
    const int h = nb * 4 + wc;       // head (wave-uniform)

    if (w < 2) {
        unsigned short* Ow = (w == 0) ? Qo : Ko;
#pragma unroll
        for (int m = 0; m < 4; ++m)
#pragma unroll
            for (int r = 0; r < 4; ++r) {
                int grow = bx * 128 + wr * 64 + m * 16 + hi * 4 + r;
                int bi = grow >> 12, tt = grow & 4095;
                unsigned short* rowp = Ow + ((long)(bi * 16 + h) * 4096 + tt) * 64;
#pragma unroll
                for (int n = 0; n < 4; ++n)
                    rowp[n * 16 + kl] = f2bf(acc[m][n][r] * sc);
            }
    } else {
#pragma unroll
        for (int m = 0; m < 4; ++m)
#pragma unroll
            for (int r = 0; r < 4; ++r) {
                int grow = bx * 128 + wr * 64 + m * 16 + hi * 4 + r;
                int bi = grow >> 12, tt = grow & 4095;
                unsigned short* hb = VTo + (long)(bi * 16 + h) * 262144;
#pragma unroll
                for (int n = 0; n < 4; ++n) {
                    int d = n * 16 + kl;
                    hb[(long)d * 4096 + tt] = f2bf(acc[m][n][r]);
                }
            }
    }
}

// ---------------------------------------------------------------------------
// Kernel 3: banded sliding-window attention, PAIRED q-blocks.
// 512 threads = 8 waves: waves 0-3 own q-block iA=2*qi (16 rows each),
// waves 4-7 own iB=2*qi+1. K/V tiles staged ONCE for both (10 tiles vs 18).
// Grid 1024 = 32 qi x 32 bh, XCD-chunk swizzled. Deferred staging + no-max
// softmax via exp2 (log2e folded into Q). Per-wave body identical to the
// R2-proven code; wave-uniform active-guard at the 2 edge tiles.
// P region = wave's own Q rows in LDS (no cross-wave hazard).
// ---------------------------------------------------------------------------
__global__ __launch_bounds__(512) void k_attn(
    const unsigned short* __restrict__ Q, const unsigned short* __restrict__ K,
    const unsigned short* __restrict__ VT, unsigned short* __restrict__ AO)
{
    __shared__ unsigned short Qs[8192];            // 128 q-rows; reused as P
    __shared__ unsigned short Ks[2][4096], Vs[2][4096];
    const int t = threadIdx.x, lane = t & 63, wid = t >> 6;
    const int kl = lane & 15, hi = lane >> 4;
    const int bid = blockIdx.x;
    const int sid = (bid & 7) * 128 + (bid >> 3);  // XCD-chunked (1024%8==0)
    const int qi = sid & 31, bh = sid >> 5;
    const int b = bh >> 4, h = bh & 15;
    const int iA = qi * 2, iB = qi * 2 + 1;
    const int myI = (wid < 4) ? iA : iB;           // this wave's q-block
    const char* qg = (const char*)(Q + ((long)bh * 4096 + qi * 128) * 64);
    const char* kg = (const char*)(K + (long)bh * 4096 * 64);
    const char* vg = (const char*)(VT + (long)bh * 64 * 4096);

    // staging geometry: Q = 1024 chunks (2/thread); K,V = 512 chunks (1/thread)
    const int cq0 = t, cq1 = t + 512;
    const int rq0 = cq0 >> 3, sq0 = ((cq0 & 7) * 16) ^ ((rq0 & 7) << 4);
    const int rq1 = cq1 >> 3, sq1 = ((cq1 & 7) * 16) ^ ((rq1 & 7) << 4);
    const int rk = t >> 3, swk = ((t & 7) * 16) ^ ((rk & 7) << 4);
    const char* kgt = kg + rk * 128 + swk;    // + j*8192
    const char* vgt = vg + rk * 8192 + swk;   // + j*128

    const int jlo = (iA >= 8) ? iA - 8 : 0;
    const int jhi = iB;

    // prologue: stage Q (both blocks) + first K/V tile
    gload_lds16(qg + rq0 * 128 + sq0, (char*)Qs + cq0 * 16);
    gload_lds16(qg + rq1 * 128 + sq1, (char*)Qs + cq1 * 16);
    gload_lds16(kgt + jlo * 8192, (char*)Ks[0] + t * 16);
    gload_lds16(vgt + jlo * 128,  (char*)Vs[0] + t * 16);
    __syncthreads();

    short8 aq[2];
    aq[0] = ldsfrag(Qs, wid * 16 + kl, hi * 16);
    aq[1] = ldsfrag(Qs, wid * 16 + kl, 64 + hi * 16);

    float lsum[4] = {0.f, 0.f, 0.f, 0.f};
    f32x4 o[4];
#pragma unroll
    for (int nt = 0; nt < 4; ++nt) o[nt] = f32x4{0.f, 0.f, 0.f, 0.f};

    const int qrow = (wid & 3) * 16 + hi * 4;  // + r (row within own q-block)
    char* pw = (char*)Qs + wid * 2048;         // per-wave P region (own Q rows)

    for (int j = jlo; j <= jhi; ++j) {
        const int buf = (j - jlo) & 1;
        if (j < jhi) {                          // deferred prefetch of j+1
            const int nb = buf ^ 1;
            gload_lds16(kgt + (j + 1) * 8192, (char*)Ks[nb] + t * 16);
            gload_lds16(vgt + (j + 1) * 128,  (char*)Vs[nb] + t * 16);
        }

        // wave-uniform activity: A-waves need j<=iA, B-waves need j>=iB-8
        const bool act = (wid < 4) ? (j <= iA) : (j >= iB - 8);
        if (act) {
            f32x4 s[4];
#pragma unroll
            for (int nt = 0; nt < 4; ++nt) {
                s[nt] = f32x4{0.f, 0.f, 0.f, 0.f};
#pragma unroll
                for (int kk = 0; kk < 2; ++kk)
                    s[nt] = __builtin_amdgcn_mfma_f32_16x16x32_bf16(
                        aq[kk], ldsfrag(Ks[buf], nt * 16 + kl, kk * 64 + hi * 16),
                        s[nt], 0, 0, 0);
            }

            if (j == myI) {               // diagonal: valid iff key <= q
#pragma unroll
                for (int nt = 0; nt < 4; ++nt) {
                    int key = nt * 16 + kl;
#pragma unroll
                    for (int r = 0; r < 4; ++r)
                        if (key > qrow + r) s[nt][r] = -1e9f;
                }
            } else if (myI - j == 8) {    // far edge: valid iff key > q
#pragma unroll
                for (int nt = 0; nt < 4; ++nt) {
                    int key = nt * 16 + kl;
#pragma unroll
                    for (int r = 0; r < 4; ++r)
                        if (key <= qrow + r) s[nt][r] = -1e9f;
                }
            }

            // p = exp2(s) (log2e pre-folded into Q; masked underflow to 0)
#pragma unroll
            for (int nt = 0; nt < 4; ++nt)
#pragma unroll
                for (int r = 0; r < 4; ++r) {
                    float p = exp2f(s[nt][r]);
                    s[nt][r] = p;
                    lsum[r] += p;
                }

            // P -> per-wave swizzled LDS (C-layout -> A-layout)
#pragma unroll
            for (int nt = 0; nt < 4; ++nt)
#pragma unroll
                for (int r = 0; r < 4; ++r) {
                    int q = hi * 4 + r;
                    int colb = (nt * 16 + kl) * 2;
                    *(unsigned short*)(pw + q * 128 + (colb ^ ((q & 7) << 4))) =
                        f2bf(s[nt][r]);
                }

            // O += P V
            short8 pa0 = ldsfrag(pw, kl, hi * 16);
            short8 pa1 = ldsfrag(pw, kl, 64 + hi * 16);
#pragma unroll
            for (int nt = 0; nt < 4; ++nt) {
                o[nt] = __builtin_amdgcn_mfma_f32_16x16x32_bf16(
                    pa0, ldsfrag(Vs[buf], nt * 16 + kl, hi * 16), o[nt], 0, 0, 0);
                o[nt] = __builtin_amdgcn_mfma_f32_16x16x32_bf16(
                    pa1, ldsfrag(Vs[buf], nt * 16 + kl, 64 + hi * 16), o[nt], 0, 0, 0);
            }
        }

        __syncthreads();   // implicit vmcnt(0): waits the j+1 prefetch; also
                           // fences buf reads before its overwrite at j+1
    }

    // single deferred lsum reduction across the 16 kl lanes (hi preserved)
#pragma unroll
    for (int d = 1; d < 16; d <<= 1)
#pragma unroll
        for (int r = 0; r < 4; ++r) lsum[r] += __shfl_xor(lsum[r], d);

    float inv[4];
#pragma unroll
    for (int r = 0; r < 4; ++r) inv[r] = 1.0f / lsum[r];
#pragma unroll
    for (int r = 0; r < 4; ++r) {
        int tt = qi * 128 + wid * 16 + hi * 4 + r;
        unsigned short* rowp = AO + ((long)(b * 4096 + tt)) * 1024 + h * 64;
#pragma unroll
        for (int nt = 0; nt < 4; ++nt)
            rowp[nt * 16 + kl] = f2bf(o[nt][r] * inv[r]);
    }
}

// ---------------------------------------------------------------------------
// Kernel 4: output projection, 128x128 tiles -> fp32 d_out. grid (64, 8):
// 512 blocks at 48KB LDS -> 2+ blocks/CU co-resident.
// ---------------------------------------------------------------------------
__global__ __launch_bounds__(256, 3) void k_gemm_out(
    const unsigned short* __restrict__ AO, const unsigned short* __restrict__ wob,
    float* __restrict__ out)
{
    extern __shared__ char smem[];
    const int bx = blockIdx.x, nb = blockIdx.y;
    f32x4 acc[4][4];
    gemm_core128(AO, wob, bx * 128, nb * 128, smem, acc);

    const int t = threadIdx.x, lane = t & 63, wid = t >> 6;
    const int wr = wid >> 1, wc = wid & 1, kl = lane & 15, hi = lane >> 4;
#pragma unroll
    for (int m = 0; m < 4; ++m)
#pragma unroll
        for (int r = 0; r < 4; ++r) {
            int grow = bx * 128 + wr * 64 + m * 16 + hi * 4 + r;
            float* rowp = out + (long)grow * 1024 + nb * 128 + wc * 64;
#pragma unroll
            for (int n = 0; n < 4; ++n)
                rowp[n * 16 + kl] = acc[m][n][r];
        }
}

// ---------------------------------------------------------------------------
extern "C" void kernel_launch(void* const* d_in, const int* in_sizes, int n_in,
                              void* d_out, int out_size, void* d_ws, size_t ws_size,
                              hipStream_t stream) {
    const float* x  = (const float*)d_in[0];
    const float* wq = (const float*)d_in[1];
    const float* wk = (const float*)d_in[2];
    const float* wv = (const float*)d_in[3];
    const float* wo = (const float*)d_in[4];

    char* ws = (char*)d_ws;
    const size_t MB = 1024 * 1024;
    unsigned short* xb  = (unsigned short*)(ws);            // 16 MB, reused as AO
    unsigned short* wqb = (unsigned short*)(ws + 16 * MB);  // 2 MB
    unsigned short* wkb = (unsigned short*)(ws + 18 * MB);
    unsigned short* wvb = (unsigned short*)(ws + 20 * MB);
    unsigned short* wob = (unsigned short*)(ws + 22 * MB);
    unsigned short* Qp  = (unsigned short*)(ws + 24 * MB);  // 16 MB each
    unsigned short* Kp  = (unsigned short*)(ws + 40 * MB);
    unsigned short* VTp = (unsigned short*)(ws + 56 * MB);  // end 72 MB
    unsigned short* AOp = xb;  // x no longer needed after QKV GEMM

    hipFuncSetAttribute((const void*)k_gemm_qkv,
                        hipFuncAttributeMaxDynamicSharedMemorySize, 73728);
    hipFuncSetAttribute((const void*)k_gemm_out,
                        hipFuncAttributeMaxDynamicSharedMemorySize, 49152);

    dim3 blk(256);
    k_cvt<<<12288, blk, 0, stream>>>(x, wq, wk, wv, wo,
                                     xb, wqb, wkb, wvb, wob);
    k_gemm_qkv<<<dim3(64, 12), 512, 73728, stream>>>(xb, wqb, wkb, wvb,
                                                     Qp, Kp, VTp);
    k_attn<<<1024, 512, 0, stream>>>(Qp, Kp, VTp, AOp);
    k_gemm_out<<<dim3(64, 8), 256, 49152, stream>>>(AOp, wob, (float*)d_out);
}